// Round 1
// baseline (679.024 us; speedup 1.0000x reference)
//
#include <hip/hip_runtime.h>

typedef __attribute__((ext_vector_type(8))) short bf16x8;
typedef __attribute__((ext_vector_type(4))) float f32x4;
typedef __attribute__((ext_vector_type(4))) int i32x4;
typedef __attribute__((ext_vector_type(4))) unsigned short u16x4;

#define LDS_STRIDE 72   // 144B row stride: 16B-aligned, uniform bank-group spread

__device__ __forceinline__ unsigned short f2bf(float f) {
    union { float f; unsigned u; } v; v.f = f;
    unsigned r = v.u + 0x7FFFu + ((v.u >> 16) & 1u);   // round-to-nearest-even
    return (unsigned short)(r >> 16);
}
__device__ __forceinline__ float fast_sigmoid(float x) { return 1.f / (1.f + __expf(-x)); }
__device__ __forceinline__ float fast_tanh(float x)    { return 1.f - 2.f / (__expf(2.f * x) + 1.f); }

// ---------------------------------------------------------------------------
// Generic NT GEMM: C[m,n] = sum_k A[m,k]*B[n,k]  (A:[M,K], B:[N,K], row-major)
// 128x128 tile, BK=64, 4 waves, wave-tile 32x128 (each wave owns whole rows).
// EPI 0: C = acc + bias[n]                  (f32 store)
// EPI 1: epart[b*256+t, nb] = sum_n tanh(acc + hproj[b,n]) * wscore[n]  (m = t*256+b)
// EPI 2: store logits = acc + bias; lsepart[m, nb] = (rowmax, rowsumexp)
// ---------------------------------------------------------------------------
template<int EPI, bool ABF, bool BBF>
__global__ __launch_bounds__(256, 2)
void gemm_nt(const void* __restrict__ Agv, const void* __restrict__ Bgv,
             const float* __restrict__ bias, float* __restrict__ Cout,
             const float* __restrict__ hproj, const float* __restrict__ wscore,
             float* __restrict__ epart, float* __restrict__ lsepart,
             int M, int N, int K)
{
    const int nbn = N >> 7;
    const int nmb = M >> 7;
    int mb, nb;
    if (EPI == 1) {
        // XCD-contiguous remap: each XCD gets a contiguous chunk of (mb,nb)
        // pairs in nb-minor order -> the 8 nb-blocks sharing an A-tile run on
        // one XCD and reuse it through that XCD's L2.
        int cpx = gridDim.x >> 3;
        int bp = (blockIdx.x & 7) * cpx + (blockIdx.x >> 3);
        mb = bp / nbn; nb = bp % nbn;
    } else {
        // nb-major: consecutive blocks share the (large) B tile
        mb = blockIdx.x % nmb; nb = blockIdx.x / nmb;
    }
    const int m0 = mb << 7, n0 = nb << 7;
    const int tid = threadIdx.x;
    const int lane = tid & 63, wid = tid >> 6;
    const int fr = lane & 15, fg = lane >> 4;
    const int srow = tid >> 1, shalf = (tid & 1) * 32;

    extern __shared__ char smem[];
    typedef unsigned short (*tile_t)[128][LDS_STRIDE];
    tile_t As = (tile_t)smem;                                    // [2][128][72]
    tile_t Bs = (tile_t)(smem + 2 * 128 * LDS_STRIDE * 2);       // [2][128][72]

    const float* Af = (const float*)Agv;
    const unsigned short* Ab = (const unsigned short*)Agv;
    const float* Bf = (const float*)Bgv;
    const unsigned short* Bb = (const unsigned short*)Bgv;

    f32x4 acc[2][8];
#pragma unroll
    for (int i = 0; i < 2; ++i)
#pragma unroll
        for (int j = 0; j < 8; ++j) acc[i][j] = (f32x4){0.f, 0.f, 0.f, 0.f};

    float a_f[32]; unsigned short a_b[32];
    float b_f[32]; unsigned short b_b[32];

    auto loadA = [&](int kt) {
        size_t base = (size_t)(m0 + srow) * K + (size_t)kt * 64 + shalf;
        if (ABF) {
#pragma unroll
            for (int j = 0; j < 4; ++j) *(i32x4*)&a_b[j * 8] = *(const i32x4*)(Ab + base + j * 8);
        } else {
#pragma unroll
            for (int j = 0; j < 8; ++j) *(f32x4*)&a_f[j * 4] = *(const f32x4*)(Af + base + j * 4);
        }
    };
    auto loadB = [&](int kt) {
        size_t base = (size_t)(n0 + srow) * K + (size_t)kt * 64 + shalf;
        if (BBF) {
#pragma unroll
            for (int j = 0; j < 4; ++j) *(i32x4*)&b_b[j * 8] = *(const i32x4*)(Bb + base + j * 8);
        } else {
#pragma unroll
            for (int j = 0; j < 8; ++j) *(f32x4*)&b_f[j * 4] = *(const f32x4*)(Bf + base + j * 4);
        }
    };
    auto storeA = [&](int buf) {
        unsigned short tA[32];
        if (ABF) {
#pragma unroll
            for (int j = 0; j < 32; ++j) tA[j] = a_b[j];
        } else {
#pragma unroll
            for (int j = 0; j < 32; ++j) tA[j] = f2bf(a_f[j]);
        }
#pragma unroll
        for (int j = 0; j < 4; ++j) *(i32x4*)&As[buf][srow][shalf + j * 8] = *(i32x4*)&tA[j * 8];
    };
    auto storeB = [&](int buf) {
        unsigned short tB[32];
        if (BBF) {
#pragma unroll
            for (int j = 0; j < 32; ++j) tB[j] = b_b[j];
        } else {
#pragma unroll
            for (int j = 0; j < 32; ++j) tB[j] = f2bf(b_f[j]);
        }
#pragma unroll
        for (int j = 0; j < 4; ++j) *(i32x4*)&Bs[buf][srow][shalf + j * 8] = *(i32x4*)&tB[j * 8];
    };

    const int nkt = K >> 6;

    loadA(0); loadB(0);
    storeA(0); storeB(0);
    __syncthreads();

    for (int kt = 0; kt < nkt; ++kt) {
        const int cur = kt & 1;
        if (kt + 1 < nkt) { loadA(kt + 1); loadB(kt + 1); }
#pragma unroll
        for (int ks = 0; ks < 2; ++ks) {
            bf16x8 av[2], bv[8];
#pragma unroll
            for (int mi = 0; mi < 2; ++mi)
                av[mi] = *(const bf16x8*)&As[cur][wid * 32 + mi * 16 + fr][ks * 32 + fg * 8];
#pragma unroll
            for (int ni = 0; ni < 8; ++ni)
                bv[ni] = *(const bf16x8*)&Bs[cur][ni * 16 + fr][ks * 32 + fg * 8];
#pragma unroll
            for (int mi = 0; mi < 2; ++mi)
#pragma unroll
                for (int ni = 0; ni < 8; ++ni)
                    acc[mi][ni] = __builtin_amdgcn_mfma_f32_16x16x32_bf16(av[mi], bv[ni], acc[mi][ni], 0, 0, 0);
        }
        if (kt + 1 < nkt) { storeA(cur ^ 1); storeB(cur ^ 1); }
        __syncthreads();
    }

    // ---- epilogues. C/D layout (m89-verified): col = lane&15, row = (lane>>4)*4 + reg.
    if (EPI == 0) {
#pragma unroll
        for (int mi = 0; mi < 2; ++mi)
#pragma unroll
            for (int r = 0; r < 4; ++r) {
                const int m = m0 + wid * 32 + mi * 16 + fg * 4 + r;
#pragma unroll
                for (int ni = 0; ni < 8; ++ni) {
                    const int col = n0 + ni * 16 + fr;
                    Cout[(size_t)m * N + col] = acc[mi][ni][r] + bias[col];
                }
            }
    } else if (EPI == 1) {
        float wsv[8];
#pragma unroll
        for (int ni = 0; ni < 8; ++ni) wsv[ni] = wscore[n0 + ni * 16 + fr];
#pragma unroll
        for (int mi = 0; mi < 2; ++mi)
#pragma unroll
            for (int r = 0; r < 4; ++r) {
                const int m = m0 + wid * 32 + mi * 16 + fg * 4 + r;
                const int bb = m & 255;           // batch (row = t*256 + b)
                const int tt = m >> 8;            // time
                const float* hp = hproj + (size_t)bb * 1024 + n0 + fr;
                float s = 0.f;
#pragma unroll
                for (int ni = 0; ni < 8; ++ni)
                    s += fast_tanh(acc[mi][ni][r] + hp[ni * 16]) * wsv[ni];
                s += __shfl_xor(s, 1); s += __shfl_xor(s, 2);
                s += __shfl_xor(s, 4); s += __shfl_xor(s, 8);
                if (fr == 0) epart[((size_t)bb * 256 + tt) * 8 + nb] = s;  // [b][t][8] for coalesced softmax reads
            }
    } else {  // EPI == 2
#pragma unroll
        for (int mi = 0; mi < 2; ++mi)
#pragma unroll
            for (int r = 0; r < 4; ++r) {
                const int m = m0 + wid * 32 + mi * 16 + fg * 4 + r;
                float vv[8];
                float mx = -3.4e38f;
#pragma unroll
                for (int ni = 0; ni < 8; ++ni) {
                    const int col = n0 + ni * 16 + fr;
                    vv[ni] = acc[mi][ni][r] + bias[col];
                    Cout[(size_t)m * N + col] = vv[ni];
                    mx = fmaxf(mx, vv[ni]);
                }
                mx = fmaxf(mx, __shfl_xor(mx, 1));
                mx = fmaxf(mx, __shfl_xor(mx, 2));
                mx = fmaxf(mx, __shfl_xor(mx, 4));
                mx = fmaxf(mx, __shfl_xor(mx, 8));
                float se = 0.f;
#pragma unroll
                for (int ni = 0; ni < 8; ++ni) se += __expf(vv[ni] - mx);
                se += __shfl_xor(se, 1); se += __shfl_xor(se, 2);
                se += __shfl_xor(se, 4); se += __shfl_xor(se, 8);
                if (fr == 0) {
                    lsepart[((size_t)m * nbn + nb) * 2]     = mx;
                    lsepart[((size_t)m * nbn + nb) * 2 + 1] = se;
                }
            }
    }
}

// ---------------------------------------------------------------------------
// prep: W_i2h f32->bf16 (1M elems) + gather emb[tokens] -> x_bf16[:,1024:2048]
// ---------------------------------------------------------------------------
__global__ void prep_kernel(const float* __restrict__ Wi2h, unsigned short* __restrict__ WiB,
                            const float* __restrict__ emb, const int* __restrict__ tokens,
                            unsigned short* __restrict__ xB)
{
    int i = blockIdx.x * 256 + threadIdx.x;
    if (i < 262144) {
        f32x4 v = *(const f32x4*)(Wi2h + (size_t)i * 4);
        u16x4 o;
#pragma unroll
        for (int j = 0; j < 4; ++j) o[j] = f2bf(v[j]);
        *(u16x4*)(WiB + (size_t)i * 4) = o;
    } else {
        int j = i - 262144;              // 65536 float4s of [256][1024]
        int b = j >> 8, h4 = j & 255;
        int tok = tokens[b];
        f32x4 v = *(const f32x4*)(emb + (size_t)tok * 1024 + h4 * 4);
        u16x4 o;
#pragma unroll
        for (int jj = 0; jj < 4; ++jj) o[jj] = f2bf(v[jj]);
        *(u16x4*)(xB + (size_t)b * 2048 + 1024 + h4 * 4) = o;
    }
}

// softmax over t per batch b; epart is [b][t][8] partials
__global__ __launch_bounds__(256) void softmax_alpha(const float* __restrict__ epart,
                                                     float* __restrict__ alpha)
{
    const int b = blockIdx.x, t = threadIdx.x;
    const int lane = t & 63, w = t >> 6;
    const float* ep = epart + ((size_t)b * 256 + t) * 8;
    float s = 0.f;
#pragma unroll
    for (int j = 0; j < 8; ++j) s += ep[j];
    __shared__ float rmax[4], rsum[4];
    float mx = s;
#pragma unroll
    for (int d = 1; d < 64; d <<= 1) mx = fmaxf(mx, __shfl_xor(mx, d));
    if (lane == 0) rmax[w] = mx;
    __syncthreads();
    mx = fmaxf(fmaxf(rmax[0], rmax[1]), fmaxf(rmax[2], rmax[3]));
    float p = __expf(s - mx);
    float sm = p;
#pragma unroll
    for (int d = 1; d < 64; d <<= 1) sm += __shfl_xor(sm, d);
    if (lane == 0) rsum[w] = sm;
    __syncthreads();
    sm = rsum[0] + rsum[1] + rsum[2] + rsum[3];
    alpha[(size_t)b * 256 + t] = p / sm;
}

// context partials: pc[tc][b][h] = sum_{t in chunk tc} alpha[b,t]*enc[t,b,h]
__global__ __launch_bounds__(256) void ctx_part(const float* __restrict__ alpha,
                                                const float* __restrict__ enc,
                                                float* __restrict__ pc)
{
    const int b = blockIdx.x, tc = blockIdx.y;
    const int h4 = threadIdx.x;
    const float* al = alpha + (size_t)b * 256 + tc * 64;
    f32x4 acc = {0.f, 0.f, 0.f, 0.f};
#pragma unroll 4
    for (int i = 0; i < 64; ++i) {
        float a = al[i];
        f32x4 e = *(const f32x4*)(enc + ((size_t)(tc * 64 + i) * 256 + b) * 1024 + h4 * 4);
        acc += e * a;
    }
    *(f32x4*)(pc + ((size_t)tc * 256 + b) * 1024 + h4 * 4) = acc;
}

// reduce context partials -> x_bf16[:,0:1024]
__global__ void ctx_fin(const float* __restrict__ pc, unsigned short* __restrict__ xB)
{
    const int b = blockIdx.x, h4 = threadIdx.x;
    f32x4 c = {0.f, 0.f, 0.f, 0.f};
#pragma unroll
    for (int tc = 0; tc < 4; ++tc)
        c += *(const f32x4*)(pc + ((size_t)tc * 256 + b) * 1024 + h4 * 4);
    u16x4 o;
#pragma unroll
    for (int j = 0; j < 4; ++j) o[j] = f2bf(c[j]);
    *(u16x4*)(xB + (size_t)b * 2048 + h4 * 4) = o;
}

// GRU elementwise (PyTorch gate order r,z,n)
__global__ void gru_kernel(const float* __restrict__ gi, const float* __restrict__ gh,
                           const float* __restrict__ h0, float* __restrict__ hnew,
                           unsigned short* __restrict__ hnB)
{
    int idx = blockIdx.x * 256 + threadIdx.x;   // 262144
    int b = idx >> 10, h = idx & 1023;
    size_t gb = (size_t)b * 3072;
    float r = fast_sigmoid(gi[gb + h]        + gh[gb + h]);
    float z = fast_sigmoid(gi[gb + 1024 + h] + gh[gb + 1024 + h]);
    float n = fast_tanh   (gi[gb + 2048 + h] + r * gh[gb + 2048 + h]);
    float hp = h0[idx];
    float hn = (1.f - z) * n + z * hp;
    hnew[idx] = hn;
    hnB[idx] = f2bf(hn);
}

// merge per-row (max,sumexp) partials -> lse[m]
__global__ void lse_reduce(const float* __restrict__ lsepart, float* __restrict__ lse, int nbn)
{
    const int m = blockIdx.x, l = threadIdx.x;  // 64 threads = 1 wave
    float mx = -3.4e38f, s = 0.f;
    for (int p = l; p < nbn; p += 64) {
        float pm = lsepart[((size_t)m * nbn + p) * 2];
        float ps = lsepart[((size_t)m * nbn + p) * 2 + 1];
        float nm = fmaxf(mx, pm);
        s = s * __expf(mx - nm) + ps * __expf(pm - nm);
        mx = nm;
    }
#pragma unroll
    for (int d = 1; d < 64; d <<= 1) {
        float om = __shfl_xor(mx, d), os = __shfl_xor(s, d);
        float nm = fmaxf(mx, om);
        s = s * __expf(mx - nm) + os * __expf(om - nm);
        mx = nm;
    }
    if (l == 0) lse[m] = mx + __logf(s);
}

// out[m,v] = logits[m,v] - lse[m]  (in place, float4)
__global__ void lsub_kernel(float* __restrict__ out, const float* __restrict__ lse)
{
    int f = blockIdx.x * 256 + threadIdx.x;     // 2,048,000 float4s; 8000 per row
    float l = lse[f / 8000];
    f32x4 v = *(const f32x4*)(out + (size_t)f * 4);
    v -= l;
    *(f32x4*)(out + (size_t)f * 4) = v;
}

// ---------------------------------------------------------------------------
extern "C" void kernel_launch(void* const* d_in, const int* in_sizes, int n_in,
                              void* d_out, int out_size, void* d_ws, size_t ws_size,
                              hipStream_t stream)
{
    const int*   tokens  = (const int*)  d_in[0];
    const float* h0      = (const float*)d_in[1];   // [1,256,1024]
    const float* enc     = (const float*)d_in[2];   // [256,256,1024]
    const float* emb     = (const float*)d_in[3];   // [32000,1024]
    const float* W_i2h   = (const float*)d_in[4];
    const float* W_h2h   = (const float*)d_in[5];
    const float* b_h2h   = (const float*)d_in[6];
    const float* w_score = (const float*)d_in[7];
    const float* W_ih    = (const float*)d_in[8];   // [3072,2048]
    const float* b_ih    = (const float*)d_in[9];
    const float* W_hh    = (const float*)d_in[10];  // [3072,1024]
    const float* b_hh    = (const float*)d_in[11];
    const float* W_out   = (const float*)d_in[12];  // [32000,1024]
    const float* b_out   = (const float*)d_in[13];

    float* out   = (float*)d_out;                       // [256,32000]
    float* hnew  = out + (size_t)256 * 32000;           // [256,1024]
    float* alpha = hnew + 256 * 1024;                   // [256,256]

    char* w = (char*)d_ws;
    unsigned short* WiB   = (unsigned short*)(w);                    // 2 MB  bf16 W_i2h
    float* hproj          = (float*)(w + (size_t)2  * (1 << 20));    // 1 MB
    float* gh             = (float*)(w + (size_t)3  * (1 << 20));    // 3 MB
    float* epart          = (float*)(w + (size_t)6  * (1 << 20));    // 2 MB  [b][t][8]
    float* pc             = (float*)(w + (size_t)8  * (1 << 20));    // 4 MB
    unsigned short* xB    = (unsigned short*)(w + (size_t)12 * (1 << 20)); // 1 MB [256][2048] bf16
    float* gi             = (float*)(w + (size_t)13 * (1 << 20));    // 3 MB
    unsigned short* hnB   = (unsigned short*)(w + (size_t)16 * (1 << 20)); // 0.5 MB
    float* lsepart        = (float*)(w + (size_t)17 * (1 << 20));    // 512 KB [256][250][2]
    float* lse            = (float*)(w + (size_t)18 * (1 << 20));    // 1 KB

    const size_t LDS = 2u * 2u * 128u * LDS_STRIDE * 2u;  // 73728 B

    // prep: W_i2h -> bf16, gather emb[tokens] -> x[:,1024:]
    prep_kernel<<<1280, 256, 0, stream>>>(W_i2h, WiB, emb, tokens, xB);
    // h_proj = h0 @ W_h2h^T + b_h2h
    gemm_nt<0, false, false><<<16, 256, LDS, stream>>>(h0, W_h2h, b_h2h, hproj,
        nullptr, nullptr, nullptr, nullptr, 256, 1024, 1024);
    // gh = h0 @ W_hh^T + b_hh
    gemm_nt<0, false, false><<<48, 256, LDS, stream>>>(h0, W_hh, b_hh, gh,
        nullptr, nullptr, nullptr, nullptr, 256, 3072, 1024);
    // e partials: fused enc@W_i2h^T -> +h_proj -> tanh -> dot w_score
    gemm_nt<1, false, true><<<4096, 256, LDS, stream>>>(enc, WiB, nullptr, nullptr,
        hproj, w_score, epart, nullptr, 65536, 1024, 1024);
    // alpha = softmax_t(e)
    softmax_alpha<<<256, 256, 0, stream>>>(epart, alpha);
    // context partials + reduce -> x_bf16[:,0:1024]
    ctx_part<<<dim3(256, 4), 256, 0, stream>>>(alpha, enc, pc);
    ctx_fin<<<256, 256, 0, stream>>>(pc, xB);
    // gi = x @ W_ih^T + b_ih
    gemm_nt<0, true, false><<<48, 256, LDS, stream>>>(xB, W_ih, b_ih, gi,
        nullptr, nullptr, nullptr, nullptr, 256, 3072, 2048);
    // GRU gates -> h_new (f32 out + bf16 copy)
    gru_kernel<<<1024, 256, 0, stream>>>(gi, gh, h0, hnew, hnB);
    // logits + per-block (max,sumexp) partials
    gemm_nt<2, true, false><<<500, 256, LDS, stream>>>(hnB, W_out, b_out, out,
        nullptr, nullptr, nullptr, lsepart, 256, 32000, 1024);
    // logsumexp reduce + subtract
    lse_reduce<<<256, 64, 0, stream>>>(lsepart, lse, 250);
    lsub_kernel<<<8000, 256, 0, stream>>>(out, lse);
}

// Round 2
// 612.065 us; speedup vs baseline: 1.1094x; 1.1094x over previous
//
#include <hip/hip_runtime.h>

typedef __attribute__((ext_vector_type(8))) short bf16x8;
typedef __attribute__((ext_vector_type(4))) float f32x4;
typedef __attribute__((ext_vector_type(4))) int i32x4;
typedef __attribute__((ext_vector_type(4))) unsigned short u16x4;
typedef __attribute__((ext_vector_type(8))) unsigned short u16x8;

#define LDS_STRIDE 72   // reg-staged kernel only

__device__ __forceinline__ unsigned short f2bf(float f) {
    union { float f; unsigned u; } v; v.f = f;
    unsigned r = v.u + 0x7FFFu + ((v.u >> 16) & 1u);   // round-to-nearest-even
    return (unsigned short)(r >> 16);
}
__device__ __forceinline__ float bf2f(unsigned short u) {
    union { unsigned u; float f; } v; v.u = ((unsigned)u) << 16; return v.f;
}
__device__ __forceinline__ float fast_sigmoid(float x) { return 1.f / (1.f + __expf(-x)); }
__device__ __forceinline__ float fast_tanh(float x)    { return 1.f - 2.f / (__expf(2.f * x) + 1.f); }

#define GLOAD_LDS16(gp, lp) __builtin_amdgcn_global_load_lds( \
    (const __attribute__((address_space(1))) void*)(gp), \
    (__attribute__((address_space(3))) void*)(lp), 16, 0, 0)

// ---------------------------------------------------------------------------
// m97-structure GEMM: both operands bf16, global_load_lds staging, linear LDS,
// double-buffered, 1 barrier/K-step. C[m,n] = sum_k A[m,k]*B[n,k].
// 128x128 tile, BK=64, 4 waves, wave-tile 32x128.
// EPI 0: C = acc + bias[n]
// EPI 1: epart[(b*256+t)*8+nb] = sum_n tanh(acc + hproj[b,n]) * wscore[n]
// EPI 2: store logits; lsepart[m,nb] = (rowmax, rowsumexp)
// ---------------------------------------------------------------------------
template<int EPI>
__global__ __launch_bounds__(256, 2)
void gemm_lds(const unsigned short* __restrict__ A, const unsigned short* __restrict__ B,
              const float* __restrict__ bias, float* __restrict__ Cout,
              const float* __restrict__ hproj, const float* __restrict__ wscore,
              float* __restrict__ epart, float* __restrict__ lsepart,
              int M, int N, int K)
{
    const int nbn = N >> 7;
    const int nmb = M >> 7;
    int mb, nb;
    if (EPI == 1) {
        // XCD-contiguous remap (verified round 1: FETCH ~= ideal)
        int cpx = gridDim.x >> 3;
        int bp = (blockIdx.x & 7) * cpx + (blockIdx.x >> 3);
        mb = bp / nbn; nb = bp % nbn;
    } else {
        mb = blockIdx.x % nmb; nb = blockIdx.x / nmb;
    }
    const int m0 = mb << 7, n0 = nb << 7;
    const int tid = threadIdx.x;
    const int lane = tid & 63, wid = tid >> 6;
    const int fr = lane & 15, fg = lane >> 4;

    __shared__ unsigned short As[2][128][64];
    __shared__ unsigned short Bs[2][128][64];

    f32x4 acc[2][8];
#pragma unroll
    for (int i = 0; i < 2; ++i)
#pragma unroll
        for (int j = 0; j < 8; ++j) acc[i][j] = (f32x4){0.f, 0.f, 0.f, 0.f};

    // staging geometry: per wave 4 issues x (A,B); each issue = 64 lanes x 16B
    // = 8 rows of 64 bf16. lane l -> row +(l>>3), col elems (l&7)*8.
    const int g_row = lane >> 3;
    const int g_col = (lane & 7) * 8;

    const int nkt = K >> 6;

    auto stage = [&](int buf, int kt) {
        const size_t kof = (size_t)kt * 64 + g_col;
#pragma unroll
        for (int i = 0; i < 4; ++i) {
            const int row = wid * 32 + i * 8;
            GLOAD_LDS16(A + (size_t)(m0 + row + g_row) * K + kof, &As[buf][row][0]);
            GLOAD_LDS16(B + (size_t)(n0 + row + g_row) * K + kof, &Bs[buf][row][0]);
        }
    };

    stage(0, 0);
    __syncthreads();

    for (int kt = 0; kt < nkt; ++kt) {
        const int cur = kt & 1;
        if (kt + 1 < nkt) stage(cur ^ 1, kt + 1);
#pragma unroll
        for (int ks = 0; ks < 2; ++ks) {
            bf16x8 av[2], bv[8];
#pragma unroll
            for (int mi = 0; mi < 2; ++mi)
                av[mi] = *(const bf16x8*)&As[cur][wid * 32 + mi * 16 + fr][ks * 32 + fg * 8];
#pragma unroll
            for (int ni = 0; ni < 8; ++ni)
                bv[ni] = *(const bf16x8*)&Bs[cur][ni * 16 + fr][ks * 32 + fg * 8];
#pragma unroll
            for (int mi = 0; mi < 2; ++mi)
#pragma unroll
                for (int ni = 0; ni < 8; ++ni)
                    acc[mi][ni] = __builtin_amdgcn_mfma_f32_16x16x32_bf16(av[mi], bv[ni], acc[mi][ni], 0, 0, 0);
        }
        __syncthreads();
    }

    // C/D layout: col = lane&15, row = (lane>>4)*4 + reg
    if (EPI == 0) {
#pragma unroll
        for (int mi = 0; mi < 2; ++mi)
#pragma unroll
            for (int r = 0; r < 4; ++r) {
                const int m = m0 + wid * 32 + mi * 16 + fg * 4 + r;
#pragma unroll
                for (int ni = 0; ni < 8; ++ni) {
                    const int col = n0 + ni * 16 + fr;
                    Cout[(size_t)m * N + col] = acc[mi][ni][r] + bias[col];
                }
            }
    } else if (EPI == 1) {
        float wsv[8];
#pragma unroll
        for (int ni = 0; ni < 8; ++ni) wsv[ni] = wscore[n0 + ni * 16 + fr];
#pragma unroll
        for (int mi = 0; mi < 2; ++mi)
#pragma unroll
            for (int r = 0; r < 4; ++r) {
                const int m = m0 + wid * 32 + mi * 16 + fg * 4 + r;
                const int bb = m & 255, tt = m >> 8;
                const float* hp = hproj + (size_t)bb * 1024 + n0 + fr;
                float s = 0.f;
#pragma unroll
                for (int ni = 0; ni < 8; ++ni)
                    s += fast_tanh(acc[mi][ni][r] + hp[ni * 16]) * wsv[ni];
                s += __shfl_xor(s, 1); s += __shfl_xor(s, 2);
                s += __shfl_xor(s, 4); s += __shfl_xor(s, 8);
                if (fr == 0) epart[((size_t)bb * 256 + tt) * 8 + nb] = s;
            }
    } else {
#pragma unroll
        for (int mi = 0; mi < 2; ++mi)
#pragma unroll
            for (int r = 0; r < 4; ++r) {
                const int m = m0 + wid * 32 + mi * 16 + fg * 4 + r;
                float vv[8];
                float mx = -3.4e38f;
#pragma unroll
                for (int ni = 0; ni < 8; ++ni) {
                    const int col = n0 + ni * 16 + fr;
                    vv[ni] = acc[mi][ni][r] + bias[col];
                    Cout[(size_t)m * N + col] = vv[ni];
                    mx = fmaxf(mx, vv[ni]);
                }
                mx = fmaxf(mx, __shfl_xor(mx, 1));
                mx = fmaxf(mx, __shfl_xor(mx, 2));
                mx = fmaxf(mx, __shfl_xor(mx, 4));
                mx = fmaxf(mx, __shfl_xor(mx, 8));
                float se = 0.f;
#pragma unroll
                for (int ni = 0; ni < 8; ++ni) se += __expf(vv[ni] - mx);
                se += __shfl_xor(se, 1); se += __shfl_xor(se, 2);
                se += __shfl_xor(se, 4); se += __shfl_xor(se, 8);
                if (fr == 0) {
                    lsepart[((size_t)m * nbn + nb) * 2]     = mx;
                    lsepart[((size_t)m * nbn + nb) * 2 + 1] = se;
                }
            }
    }
}

// ---------------------------------------------------------------------------
// Reg-staged GEMM (round-1, passing) — kept for small GEMMs + logits GEMM.
// ---------------------------------------------------------------------------
template<int EPI, bool ABF, bool BBF>
__global__ __launch_bounds__(256, 2)
void gemm_rs(const void* __restrict__ Agv, const void* __restrict__ Bgv,
             const float* __restrict__ bias, float* __restrict__ Cout,
             const float* __restrict__ hproj, const float* __restrict__ wscore,
             float* __restrict__ epart, float* __restrict__ lsepart,
             int M, int N, int K)
{
    const int nbn = N >> 7;
    const int nmb = M >> 7;
    int mb, nb;
    if (EPI == 1) {
        int cpx = gridDim.x >> 3;
        int bp = (blockIdx.x & 7) * cpx + (blockIdx.x >> 3);
        mb = bp / nbn; nb = bp % nbn;
    } else {
        mb = blockIdx.x % nmb; nb = blockIdx.x / nmb;
    }
    const int m0 = mb << 7, n0 = nb << 7;
    const int tid = threadIdx.x;
    const int lane = tid & 63, wid = tid >> 6;
    const int fr = lane & 15, fg = lane >> 4;
    const int srow = tid >> 1, shalf = (tid & 1) * 32;

    extern __shared__ char smem[];
    typedef unsigned short (*tile_t)[128][LDS_STRIDE];
    tile_t As = (tile_t)smem;
    tile_t Bs = (tile_t)(smem + 2 * 128 * LDS_STRIDE * 2);

    const float* Af = (const float*)Agv;
    const unsigned short* Ab = (const unsigned short*)Agv;
    const float* Bf = (const float*)Bgv;
    const unsigned short* Bb = (const unsigned short*)Bgv;

    f32x4 acc[2][8];
#pragma unroll
    for (int i = 0; i < 2; ++i)
#pragma unroll
        for (int j = 0; j < 8; ++j) acc[i][j] = (f32x4){0.f, 0.f, 0.f, 0.f};

    float a_f[32]; unsigned short a_b[32];
    float b_f[32]; unsigned short b_b[32];

    auto loadA = [&](int kt) {
        size_t base = (size_t)(m0 + srow) * K + (size_t)kt * 64 + shalf;
        if (ABF) {
#pragma unroll
            for (int j = 0; j < 4; ++j) *(i32x4*)&a_b[j * 8] = *(const i32x4*)(Ab + base + j * 8);
        } else {
#pragma unroll
            for (int j = 0; j < 8; ++j) *(f32x4*)&a_f[j * 4] = *(const f32x4*)(Af + base + j * 4);
        }
    };
    auto loadB = [&](int kt) {
        size_t base = (size_t)(n0 + srow) * K + (size_t)kt * 64 + shalf;
        if (BBF) {
#pragma unroll
            for (int j = 0; j < 4; ++j) *(i32x4*)&b_b[j * 8] = *(const i32x4*)(Bb + base + j * 8);
        } else {
#pragma unroll
            for (int j = 0; j < 8; ++j) *(f32x4*)&b_f[j * 4] = *(const f32x4*)(Bf + base + j * 4);
        }
    };
    auto storeA = [&](int buf) {
        unsigned short tA[32];
        if (ABF) {
#pragma unroll
            for (int j = 0; j < 32; ++j) tA[j] = a_b[j];
        } else {
#pragma unroll
            for (int j = 0; j < 32; ++j) tA[j] = f2bf(a_f[j]);
        }
#pragma unroll
        for (int j = 0; j < 4; ++j) *(i32x4*)&As[buf][srow][shalf + j * 8] = *(i32x4*)&tA[j * 8];
    };
    auto storeB = [&](int buf) {
        unsigned short tB[32];
        if (BBF) {
#pragma unroll
            for (int j = 0; j < 32; ++j) tB[j] = b_b[j];
        } else {
#pragma unroll
            for (int j = 0; j < 32; ++j) tB[j] = f2bf(b_f[j]);
        }
#pragma unroll
        for (int j = 0; j < 4; ++j) *(i32x4*)&Bs[buf][srow][shalf + j * 8] = *(i32x4*)&tB[j * 8];
    };

    const int nkt = K >> 6;

    loadA(0); loadB(0);
    storeA(0); storeB(0);
    __syncthreads();

    for (int kt = 0; kt < nkt; ++kt) {
        const int cur = kt & 1;
        if (kt + 1 < nkt) { loadA(kt + 1); loadB(kt + 1); }
#pragma unroll
        for (int ks = 0; ks < 2; ++ks) {
            bf16x8 av[2], bv[8];
#pragma unroll
            for (int mi = 0; mi < 2; ++mi)
                av[mi] = *(const bf16x8*)&As[cur][wid * 32 + mi * 16 + fr][ks * 32 + fg * 8];
#pragma unroll
            for (int ni = 0; ni < 8; ++ni)
                bv[ni] = *(const bf16x8*)&Bs[cur][ni * 16 + fr][ks * 32 + fg * 8];
#pragma unroll
            for (int mi = 0; mi < 2; ++mi)
#pragma unroll
                for (int ni = 0; ni < 8; ++ni)
                    acc[mi][ni] = __builtin_amdgcn_mfma_f32_16x16x32_bf16(av[mi], bv[ni], acc[mi][ni], 0, 0, 0);
        }
        if (kt + 1 < nkt) { storeA(cur ^ 1); storeB(cur ^ 1); }
        __syncthreads();
    }

    if (EPI == 0) {
#pragma unroll
        for (int mi = 0; mi < 2; ++mi)
#pragma unroll
            for (int r = 0; r < 4; ++r) {
                const int m = m0 + wid * 32 + mi * 16 + fg * 4 + r;
#pragma unroll
                for (int ni = 0; ni < 8; ++ni) {
                    const int col = n0 + ni * 16 + fr;
                    Cout[(size_t)m * N + col] = acc[mi][ni][r] + bias[col];
                }
            }
    } else if (EPI == 1) {
        float wsv[8];
#pragma unroll
        for (int ni = 0; ni < 8; ++ni) wsv[ni] = wscore[n0 + ni * 16 + fr];
#pragma unroll
        for (int mi = 0; mi < 2; ++mi)
#pragma unroll
            for (int r = 0; r < 4; ++r) {
                const int m = m0 + wid * 32 + mi * 16 + fg * 4 + r;
                const int bb = m & 255, tt = m >> 8;
                const float* hp = hproj + (size_t)bb * 1024 + n0 + fr;
                float s = 0.f;
#pragma unroll
                for (int ni = 0; ni < 8; ++ni)
                    s += fast_tanh(acc[mi][ni][r] + hp[ni * 16]) * wsv[ni];
                s += __shfl_xor(s, 1); s += __shfl_xor(s, 2);
                s += __shfl_xor(s, 4); s += __shfl_xor(s, 8);
                if (fr == 0) epart[((size_t)bb * 256 + tt) * 8 + nb] = s;
            }
    } else {
#pragma unroll
        for (int mi = 0; mi < 2; ++mi)
#pragma unroll
            for (int r = 0; r < 4; ++r) {
                const int m = m0 + wid * 32 + mi * 16 + fg * 4 + r;
                float vv[8];
                float mx = -3.4e38f;
#pragma unroll
                for (int ni = 0; ni < 8; ++ni) {
                    const int col = n0 + ni * 16 + fr;
                    vv[ni] = acc[mi][ni][r] + bias[col];
                    Cout[(size_t)m * N + col] = vv[ni];
                    mx = fmaxf(mx, vv[ni]);
                }
                mx = fmaxf(mx, __shfl_xor(mx, 1));
                mx = fmaxf(mx, __shfl_xor(mx, 2));
                mx = fmaxf(mx, __shfl_xor(mx, 4));
                mx = fmaxf(mx, __shfl_xor(mx, 8));
                float se = 0.f;
#pragma unroll
                for (int ni = 0; ni < 8; ++ni) se += __expf(vv[ni] - mx);
                se += __shfl_xor(se, 1); se += __shfl_xor(se, 2);
                se += __shfl_xor(se, 4); se += __shfl_xor(se, 8);
                if (fr == 0) {
                    lsepart[((size_t)m * nbn + nb) * 2]     = mx;
                    lsepart[((size_t)m * nbn + nb) * 2 + 1] = se;
                }
            }
    }
}

// ---------------------------------------------------------------------------
// prep_all: enc f32->bf16 (16.78M f4) + W_i2h f32->bf16 (262144 f4)
//           + emb gather -> xB[:,1024:2048] (65536 f4). Grid-stride.
// ---------------------------------------------------------------------------
__global__ void prep_all(const float* __restrict__ enc, unsigned short* __restrict__ encB,
                         const float* __restrict__ Wi2h, unsigned short* __restrict__ WiB,
                         const float* __restrict__ emb, const int* __restrict__ tokens,
                         unsigned short* __restrict__ xB)
{
    const int ENC4 = 16777216, WI4 = 262144, EMB4 = 65536;
    const int total = ENC4 + WI4 + EMB4;
    for (int i = blockIdx.x * 256 + threadIdx.x; i < total; i += gridDim.x * 256) {
        f32x4 v; unsigned short* dst;
        if (i < ENC4) {
            v = *(const f32x4*)(enc + (size_t)i * 4);
            dst = encB + (size_t)i * 4;
        } else if (i < ENC4 + WI4) {
            int j = i - ENC4;
            v = *(const f32x4*)(Wi2h + (size_t)j * 4);
            dst = WiB + (size_t)j * 4;
        } else {
            int j = i - ENC4 - WI4;
            int b = j >> 8, h4 = j & 255;
            v = *(const f32x4*)(emb + (size_t)tokens[b] * 1024 + h4 * 4);
            dst = xB + (size_t)b * 2048 + 1024 + h4 * 4;
        }
        u16x4 o;
#pragma unroll
        for (int j = 0; j < 4; ++j) o[j] = f2bf(v[j]);
        *(u16x4*)dst = o;
    }
}

// fallback prep (round-1): W_i2h conv + emb gather only
__global__ void prep_kernel(const float* __restrict__ Wi2h, unsigned short* __restrict__ WiB,
                            const float* __restrict__ emb, const int* __restrict__ tokens,
                            unsigned short* __restrict__ xB)
{
    int i = blockIdx.x * 256 + threadIdx.x;
    if (i < 262144) {
        f32x4 v = *(const f32x4*)(Wi2h + (size_t)i * 4);
        u16x4 o;
#pragma unroll
        for (int j = 0; j < 4; ++j) o[j] = f2bf(v[j]);
        *(u16x4*)(WiB + (size_t)i * 4) = o;
    } else {
        int j = i - 262144;
        int b = j >> 8, h4 = j & 255;
        int tok = tokens[b];
        f32x4 v = *(const f32x4*)(emb + (size_t)tok * 1024 + h4 * 4);
        u16x4 o;
#pragma unroll
        for (int jj = 0; jj < 4; ++jj) o[jj] = f2bf(v[jj]);
        *(u16x4*)(xB + (size_t)b * 2048 + 1024 + h4 * 4) = o;
    }
}

// softmax over t per batch b; epart is [b][t][8] partials
__global__ __launch_bounds__(256) void softmax_alpha(const float* __restrict__ epart,
                                                     float* __restrict__ alpha)
{
    const int b = blockIdx.x, t = threadIdx.x;
    const int lane = t & 63, w = t >> 6;
    const float* ep = epart + ((size_t)b * 256 + t) * 8;
    float s = 0.f;
#pragma unroll
    for (int j = 0; j < 8; ++j) s += ep[j];
    __shared__ float rmax[4], rsum[4];
    float mx = s;
#pragma unroll
    for (int d = 1; d < 64; d <<= 1) mx = fmaxf(mx, __shfl_xor(mx, d));
    if (lane == 0) rmax[w] = mx;
    __syncthreads();
    mx = fmaxf(fmaxf(rmax[0], rmax[1]), fmaxf(rmax[2], rmax[3]));
    float p = __expf(s - mx);
    float sm = p;
#pragma unroll
    for (int d = 1; d < 64; d <<= 1) sm += __shfl_xor(sm, d);
    if (lane == 0) rsum[w] = sm;
    __syncthreads();
    sm = rsum[0] + rsum[1] + rsum[2] + rsum[3];
    alpha[(size_t)b * 256 + t] = p / sm;
}

// context partials from bf16 enc: 128 threads, 8 bf16 each
__global__ __launch_bounds__(128) void ctx_part_bf(const float* __restrict__ alpha,
                                                   const unsigned short* __restrict__ encB,
                                                   float* __restrict__ pc)
{
    const int b = blockIdx.x, tc = blockIdx.y;
    const int h8 = threadIdx.x;          // 0..127
    const float* al = alpha + (size_t)b * 256 + tc * 64;
    float acc[8];
#pragma unroll
    for (int j = 0; j < 8; ++j) acc[j] = 0.f;
#pragma unroll 4
    for (int i = 0; i < 64; ++i) {
        float a = al[i];
        u16x8 e = *(const u16x8*)(encB + ((size_t)(tc * 64 + i) * 256 + b) * 1024 + h8 * 8);
#pragma unroll
        for (int j = 0; j < 8; ++j) acc[j] += bf2f(e[j]) * a;
    }
    float* d = pc + ((size_t)tc * 256 + b) * 1024 + h8 * 8;
    *(f32x4*)d = *(f32x4*)&acc[0];
    *(f32x4*)(d + 4) = *(f32x4*)&acc[4];
}

// fallback f32 ctx_part
__global__ __launch_bounds__(256) void ctx_part(const float* __restrict__ alpha,
                                                const float* __restrict__ enc,
                                                float* __restrict__ pc)
{
    const int b = blockIdx.x, tc = blockIdx.y;
    const int h4 = threadIdx.x;
    const float* al = alpha + (size_t)b * 256 + tc * 64;
    f32x4 acc = {0.f, 0.f, 0.f, 0.f};
#pragma unroll 4
    for (int i = 0; i < 64; ++i) {
        float a = al[i];
        f32x4 e = *(const f32x4*)(enc + ((size_t)(tc * 64 + i) * 256 + b) * 1024 + h4 * 4);
        acc += e * a;
    }
    *(f32x4*)(pc + ((size_t)tc * 256 + b) * 1024 + h4 * 4) = acc;
}

// reduce context partials -> x_bf16[:,0:1024]
__global__ void ctx_fin(const float* __restrict__ pc, unsigned short* __restrict__ xB)
{
    const int b = blockIdx.x, h4 = threadIdx.x;
    f32x4 c = {0.f, 0.f, 0.f, 0.f};
#pragma unroll
    for (int tc = 0; tc < 4; ++tc)
        c += *(const f32x4*)(pc + ((size_t)tc * 256 + b) * 1024 + h4 * 4);
    u16x4 o;
#pragma unroll
    for (int j = 0; j < 4; ++j) o[j] = f2bf(c[j]);
    *(u16x4*)(xB + (size_t)b * 2048 + h4 * 4) = o;
}

// GRU elementwise (PyTorch gate order r,z,n)
__global__ void gru_kernel(const float* __restrict__ gi, const float* __restrict__ gh,
                           const float* __restrict__ h0, float* __restrict__ hnew,
                           unsigned short* __restrict__ hnB)
{
    int idx = blockIdx.x * 256 + threadIdx.x;   // 262144
    int b = idx >> 10, h = idx & 1023;
    size_t gb = (size_t)b * 3072;
    float r = fast_sigmoid(gi[gb + h]        + gh[gb + h]);
    float z = fast_sigmoid(gi[gb + 1024 + h] + gh[gb + 1024 + h]);
    float n = fast_tanh   (gi[gb + 2048 + h] + r * gh[gb + 2048 + h]);
    float hp = h0[idx];
    float hn = (1.f - z) * n + z * hp;
    hnew[idx] = hn;
    hnB[idx] = f2bf(hn);
}

// merge per-row (max,sumexp) partials -> lse[m]
__global__ void lse_reduce(const float* __restrict__ lsepart, float* __restrict__ lse, int nbn)
{
    const int m = blockIdx.x, l = threadIdx.x;  // 64 threads
    float mx = -3.4e38f, s = 0.f;
    for (int p = l; p < nbn; p += 64) {
        float pm = lsepart[((size_t)m * nbn + p) * 2];
        float ps = lsepart[((size_t)m * nbn + p) * 2 + 1];
        float nm = fmaxf(mx, pm);
        s = s * __expf(mx - nm) + ps * __expf(pm - nm);
        mx = nm;
    }
#pragma unroll
    for (int d = 1; d < 64; d <<= 1) {
        float om = __shfl_xor(mx, d), os = __shfl_xor(s, d);
        float nm = fmaxf(mx, om);
        s = s * __expf(mx - nm) + os * __expf(om - nm);
        mx = nm;
    }
    if (l == 0) lse[m] = mx + __logf(s);
}

// out[m,v] = logits[m,v] - lse[m]
__global__ void lsub_kernel(float* __restrict__ out, const float* __restrict__ lse)
{
    int f = blockIdx.x * 256 + threadIdx.x;     // 2,048,000 float4s
    float l = lse[f / 8000];
    f32x4 v = *(const f32x4*)(out + (size_t)f * 4);
    v -= l;
    *(f32x4*)(out + (size_t)f * 4) = v;
}

// ---------------------------------------------------------------------------
extern "C" void kernel_launch(void* const* d_in, const int* in_sizes, int n_in,
                              void* d_out, int out_size, void* d_ws, size_t ws_size,
                              hipStream_t stream)
{
    const int*   tokens  = (const int*)  d_in[0];
    const float* h0      = (const float*)d_in[1];
    const float* enc     = (const float*)d_in[2];
    const float* emb     = (const float*)d_in[3];
    const float* W_i2h   = (const float*)d_in[4];
    const float* W_h2h   = (const float*)d_in[5];
    const float* b_h2h   = (const float*)d_in[6];
    const float* w_score = (const float*)d_in[7];
    const float* W_ih    = (const float*)d_in[8];
    const float* b_ih    = (const float*)d_in[9];
    const float* W_hh    = (const float*)d_in[10];
    const float* b_hh    = (const float*)d_in[11];
    const float* W_out   = (const float*)d_in[12];
    const float* b_out   = (const float*)d_in[13];

    float* out   = (float*)d_out;
    float* hnew  = out + (size_t)256 * 32000;
    float* alpha = hnew + 256 * 1024;

    const size_t RS_LDS = 2u * 2u * 128u * LDS_STRIDE * 2u;  // 73728 B

    char* w = (char*)d_ws;
    const size_t NEED = (size_t)153 * (1 << 20);

    if (ws_size >= NEED) {
        // ---- main path: pre-converted bf16 enc + global_load_lds GEMM
        unsigned short* encB  = (unsigned short*)(w);                          // 128 MB
        unsigned short* WiB   = (unsigned short*)(w + (size_t)128 * (1 << 20)); // 2 MB
        float* hproj          = (float*)(w + (size_t)130 * (1 << 20));          // 1 MB
        float* gh             = (float*)(w + (size_t)131 * (1 << 20));          // 3 MB
        float* epart          = (float*)(w + (size_t)134 * (1 << 20));          // 2 MB
        float* pc             = (float*)(w + (size_t)136 * (1 << 20));          // 4 MB
        unsigned short* xB    = (unsigned short*)(w + (size_t)140 * (1 << 20)); // 1 MB
        float* gi             = (float*)(w + (size_t)141 * (1 << 20));          // 3 MB
        unsigned short* hnB   = (unsigned short*)(w + (size_t)144 * (1 << 20)); // 0.5 MB
        float* lsepart        = (float*)(w + (size_t)145 * (1 << 20));          // 0.5 MB
        float* lse            = (float*)(w + (size_t)146 * (1 << 20));          // 1 KB

        prep_all<<<2048, 256, 0, stream>>>(enc, encB, W_i2h, WiB, emb, tokens, xB);
        gemm_rs<0, false, false><<<16, 256, RS_LDS, stream>>>(h0, W_h2h, b_h2h, hproj,
            nullptr, nullptr, nullptr, nullptr, 256, 1024, 1024);
        gemm_rs<0, false, false><<<48, 256, RS_LDS, stream>>>(h0, W_hh, b_hh, gh,
            nullptr, nullptr, nullptr, nullptr, 256, 3072, 1024);
        gemm_lds<1><<<4096, 256, 0, stream>>>(encB, WiB, nullptr, nullptr,
            hproj, w_score, epart, nullptr, 65536, 1024, 1024);
        softmax_alpha<<<256, 256, 0, stream>>>(epart, alpha);
        ctx_part_bf<<<dim3(256, 4), 128, 0, stream>>>(alpha, encB, pc);
        ctx_fin<<<256, 256, 0, stream>>>(pc, xB);
        gemm_rs<0, true, false><<<48, 256, RS_LDS, stream>>>(xB, W_ih, b_ih, gi,
            nullptr, nullptr, nullptr, nullptr, 256, 3072, 2048);
        gru_kernel<<<1024, 256, 0, stream>>>(gi, gh, h0, hnew, hnB);
        gemm_rs<2, true, false><<<500, 256, RS_LDS, stream>>>(hnB, W_out, b_out, out,
            nullptr, nullptr, nullptr, lsepart, 256, 32000, 1024);
        lse_reduce<<<256, 64, 0, stream>>>(lsepart, lse, 250);
        lsub_kernel<<<8000, 256, 0, stream>>>(out, lse);
    } else {
        // ---- fallback: round-1 path (18 MB workspace)
        unsigned short* WiB   = (unsigned short*)(w);
        float* hproj          = (float*)(w + (size_t)2  * (1 << 20));
        float* gh             = (float*)(w + (size_t)3  * (1 << 20));
        float* epart          = (float*)(w + (size_t)6  * (1 << 20));
        float* pc             = (float*)(w + (size_t)8  * (1 << 20));
        unsigned short* xB    = (unsigned short*)(w + (size_t)12 * (1 << 20));
        float* gi             = (float*)(w + (size_t)13 * (1 << 20));
        unsigned short* hnB   = (unsigned short*)(w + (size_t)16 * (1 << 20));
        float* lsepart        = (float*)(w + (size_t)17 * (1 << 20));
        float* lse            = (float*)(w + (size_t)18 * (1 << 20));

        prep_kernel<<<1280, 256, 0, stream>>>(W_i2h, WiB, emb, tokens, xB);
        gemm_rs<0, false, false><<<16, 256, RS_LDS, stream>>>(h0, W_h2h, b_h2h, hproj,
            nullptr, nullptr, nullptr, nullptr, 256, 1024, 1024);
        gemm_rs<0, false, false><<<48, 256, RS_LDS, stream>>>(h0, W_hh, b_hh, gh,
            nullptr, nullptr, nullptr, nullptr, 256, 3072, 1024);
        gemm_rs<1, false, true><<<4096, 256, RS_LDS, stream>>>(enc, WiB, nullptr, nullptr,
            hproj, w_score, epart, nullptr, 65536, 1024, 1024);
        softmax_alpha<<<256, 256, 0, stream>>>(epart, alpha);
        ctx_part<<<dim3(256, 4), 256, 0, stream>>>(alpha, enc, pc);
        ctx_fin<<<256, 256, 0, stream>>>(pc, xB);
        gemm_rs<0, true, false><<<48, 256, RS_LDS, stream>>>(xB, W_ih, b_ih, gi,
            nullptr, nullptr, nullptr, nullptr, 256, 3072, 2048);
        gru_kernel<<<1024, 256, 0, stream>>>(gi, gh, h0, hnew, hnB);
        gemm_rs<2, true, false><<<500, 256, RS_LDS, stream>>>(hnB, W_out, b_out, out,
            nullptr, nullptr, nullptr, lsepart, 256, 32000, 1024);
        lse_reduce<<<256, 64, 0, stream>>>(lsepart, lse, 250);
        lsub_kernel<<<8000, 256, 0, stream>>>(out, lse);
    }
}

// Round 3
// 570.231 us; speedup vs baseline: 1.1908x; 1.0734x over previous
//
#include <hip/hip_runtime.h>

typedef __attribute__((ext_vector_type(8))) short bf16x8;
typedef __attribute__((ext_vector_type(4))) float f32x4;
typedef __attribute__((ext_vector_type(4))) int i32x4;
typedef __attribute__((ext_vector_type(4))) unsigned short u16x4;
typedef __attribute__((ext_vector_type(8))) unsigned short u16x8;

#define LDS_STRIDE 72   // reg-staged kernel only

__device__ __forceinline__ unsigned short f2bf(float f) {
    union { float f; unsigned u; } v; v.f = f;
    unsigned r = v.u + 0x7FFFu + ((v.u >> 16) & 1u);   // round-to-nearest-even
    return (unsigned short)(r >> 16);
}
__device__ __forceinline__ float bf2f(unsigned short u) {
    union { unsigned u; float f; } v; v.u = ((unsigned)u) << 16; return v.f;
}
__device__ __forceinline__ float fast_sigmoid(float x) { return 1.f / (1.f + __expf(-x)); }
__device__ __forceinline__ float fast_tanh(float x)    { return 1.f - 2.f / (__expf(2.f * x) + 1.f); }

#define GLOAD_LDS16(gp, lp) __builtin_amdgcn_global_load_lds( \
    (const __attribute__((address_space(1))) void*)(gp), \
    (__attribute__((address_space(3))) void*)(lp), 16, 0, 0)

// ---------------------------------------------------------------------------
// m97-structure GEMM + T2 XOR swizzle (rule #21: linear LDS dest, inverse-
// swizzled global source, swizzled ds_read).  Swizzle: elem col ^= (row&7)<<3.
// C[m,n] = sum_k A[m,k]*B[n,k]; A,B bf16 row-major [.,K].
// 128x128 tile, BK=64, 4 waves, wave-tile 32x128.
// EPI 0: C = acc + bias[n]
// EPI 1: epart[(b*256+t)*8+nb] = sum_n tanh(acc + hproj[b,n]) * wscore[n]
// EPI 2: store logits; lsepart[m,nb] = (rowmax, rowsumexp)
// ---------------------------------------------------------------------------
template<int EPI>
__global__ __launch_bounds__(256, 2)
void gemm_lds(const unsigned short* __restrict__ A, const unsigned short* __restrict__ B,
              const float* __restrict__ bias, float* __restrict__ Cout,
              const float* __restrict__ hproj, const float* __restrict__ wscore,
              float* __restrict__ epart, float* __restrict__ lsepart,
              int M, int N, int K)
{
    const int nbn = N >> 7;
    const int nmb = M >> 7;
    int mb, nb;
    if (EPI == 1) {
        // XCD-contiguous remap (verified r1/r2: FETCH ~= ideal)
        int cpx = gridDim.x >> 3;
        int bp = (blockIdx.x & 7) * cpx + (blockIdx.x >> 3);
        mb = bp / nbn; nb = bp % nbn;
    } else {
        mb = blockIdx.x % nmb; nb = blockIdx.x / nmb;
    }
    const int m0 = mb << 7, n0 = nb << 7;
    const int tid = threadIdx.x;
    const int lane = tid & 63, wid = tid >> 6;
    const int fr = lane & 15, fg = lane >> 4;

    __shared__ unsigned short As[2][128][64];
    __shared__ unsigned short Bs[2][128][64];

    f32x4 acc[2][8];
#pragma unroll
    for (int i = 0; i < 2; ++i)
#pragma unroll
        for (int j = 0; j < 8; ++j) acc[i][j] = (f32x4){0.f, 0.f, 0.f, 0.f};

    // staging: lane l covers LDS row +(l>>3), elem cols (l&7)*8..+8 (linear).
    // inverse-swizzled global col: ((l&7) ^ (l>>3)) * 8   [row&7 == l>>3]
    const int g_row = lane >> 3;
    const int g_col = ((lane & 7) ^ (lane >> 3)) << 3;

    const int nkt = K >> 6;

    auto stage = [&](int buf, int kt) {
        const size_t kof = (size_t)kt * 64 + g_col;
#pragma unroll
        for (int i = 0; i < 4; ++i) {
            const int row = wid * 32 + i * 8;
            GLOAD_LDS16(A + (size_t)(m0 + row + g_row) * K + kof, &As[buf][row][0]);
            GLOAD_LDS16(B + (size_t)(n0 + row + g_row) * K + kof, &Bs[buf][row][0]);
        }
    };

    stage(0, 0);
    __syncthreads();

    const int swz = (fr & 7) << 3;   // both A and B fragment rows have row&7 == fr&7

    for (int kt = 0; kt < nkt; ++kt) {
        const int cur = kt & 1;
        if (kt + 1 < nkt) stage(cur ^ 1, kt + 1);
#pragma unroll
        for (int ks = 0; ks < 2; ++ks) {
            const int col = (ks * 32 + fg * 8) ^ swz;
            bf16x8 av[2], bv[8];
#pragma unroll
            for (int mi = 0; mi < 2; ++mi)
                av[mi] = *(const bf16x8*)&As[cur][wid * 32 + mi * 16 + fr][col];
#pragma unroll
            for (int ni = 0; ni < 8; ++ni)
                bv[ni] = *(const bf16x8*)&Bs[cur][ni * 16 + fr][col];
#pragma unroll
            for (int mi = 0; mi < 2; ++mi)
#pragma unroll
                for (int ni = 0; ni < 8; ++ni)
                    acc[mi][ni] = __builtin_amdgcn_mfma_f32_16x16x32_bf16(av[mi], bv[ni], acc[mi][ni], 0, 0, 0);
        }
        __syncthreads();
    }

    // C/D layout: col = lane&15, row = (lane>>4)*4 + reg
    if (EPI == 0) {
#pragma unroll
        for (int mi = 0; mi < 2; ++mi)
#pragma unroll
            for (int r = 0; r < 4; ++r) {
                const int m = m0 + wid * 32 + mi * 16 + fg * 4 + r;
#pragma unroll
                for (int ni = 0; ni < 8; ++ni) {
                    const int col = n0 + ni * 16 + fr;
                    Cout[(size_t)m * N + col] = acc[mi][ni][r] + bias[col];
                }
            }
    } else if (EPI == 1) {
        float wsv[8];
#pragma unroll
        for (int ni = 0; ni < 8; ++ni) wsv[ni] = wscore[n0 + ni * 16 + fr];
#pragma unroll
        for (int mi = 0; mi < 2; ++mi)
#pragma unroll
            for (int r = 0; r < 4; ++r) {
                const int m = m0 + wid * 32 + mi * 16 + fg * 4 + r;
                const int bb = m & 255, tt = m >> 8;
                const float* hp = hproj + (size_t)bb * 1024 + n0 + fr;
                float s = 0.f;
#pragma unroll
                for (int ni = 0; ni < 8; ++ni)
                    s += fast_tanh(acc[mi][ni][r] + hp[ni * 16]) * wsv[ni];
                s += __shfl_xor(s, 1); s += __shfl_xor(s, 2);
                s += __shfl_xor(s, 4); s += __shfl_xor(s, 8);
                if (fr == 0) epart[((size_t)bb * 256 + tt) * 8 + nb] = s;
            }
    } else {
#pragma unroll
        for (int mi = 0; mi < 2; ++mi)
#pragma unroll
            for (int r = 0; r < 4; ++r) {
                const int m = m0 + wid * 32 + mi * 16 + fg * 4 + r;
                float vv[8];
                float mx = -3.4e38f;
#pragma unroll
                for (int ni = 0; ni < 8; ++ni) {
                    const int col = n0 + ni * 16 + fr;
                    vv[ni] = acc[mi][ni][r] + bias[col];
                    Cout[(size_t)m * N + col] = vv[ni];
                    mx = fmaxf(mx, vv[ni]);
                }
                mx = fmaxf(mx, __shfl_xor(mx, 1));
                mx = fmaxf(mx, __shfl_xor(mx, 2));
                mx = fmaxf(mx, __shfl_xor(mx, 4));
                mx = fmaxf(mx, __shfl_xor(mx, 8));
                float se = 0.f;
#pragma unroll
                for (int ni = 0; ni < 8; ++ni) se += __expf(vv[ni] - mx);
                se += __shfl_xor(se, 1); se += __shfl_xor(se, 2);
                se += __shfl_xor(se, 4); se += __shfl_xor(se, 8);
                if (fr == 0) {
                    lsepart[((size_t)m * nbn + nb) * 2]     = mx;
                    lsepart[((size_t)m * nbn + nb) * 2 + 1] = se;
                }
            }
    }
}

// ---------------------------------------------------------------------------
// Reg-staged GEMM (round-1) — small GEMMs + logits GEMM (f32 weights in HBM).
// ---------------------------------------------------------------------------
template<int EPI, bool ABF, bool BBF>
__global__ __launch_bounds__(256, 2)
void gemm_rs(const void* __restrict__ Agv, const void* __restrict__ Bgv,
             const float* __restrict__ bias, float* __restrict__ Cout,
             const float* __restrict__ hproj, const float* __restrict__ wscore,
             float* __restrict__ epart, float* __restrict__ lsepart,
             int M, int N, int K)
{
    const int nbn = N >> 7;
    const int nmb = M >> 7;
    int mb, nb;
    if (EPI == 1) {
        int cpx = gridDim.x >> 3;
        int bp = (blockIdx.x & 7) * cpx + (blockIdx.x >> 3);
        mb = bp / nbn; nb = bp % nbn;
    } else {
        mb = blockIdx.x % nmb; nb = blockIdx.x / nmb;
    }
    const int m0 = mb << 7, n0 = nb << 7;
    const int tid = threadIdx.x;
    const int lane = tid & 63, wid = tid >> 6;
    const int fr = lane & 15, fg = lane >> 4;
    const int srow = tid >> 1, shalf = (tid & 1) * 32;

    extern __shared__ char smem[];
    typedef unsigned short (*tile_t)[128][LDS_STRIDE];
    tile_t As = (tile_t)smem;
    tile_t Bs = (tile_t)(smem + 2 * 128 * LDS_STRIDE * 2);

    const float* Af = (const float*)Agv;
    const unsigned short* Ab = (const unsigned short*)Agv;
    const float* Bf = (const float*)Bgv;
    const unsigned short* Bb = (const unsigned short*)Bgv;

    f32x4 acc[2][8];
#pragma unroll
    for (int i = 0; i < 2; ++i)
#pragma unroll
        for (int j = 0; j < 8; ++j) acc[i][j] = (f32x4){0.f, 0.f, 0.f, 0.f};

    float a_f[32]; unsigned short a_b[32];
    float b_f[32]; unsigned short b_b[32];

    auto loadA = [&](int kt) {
        size_t base = (size_t)(m0 + srow) * K + (size_t)kt * 64 + shalf;
        if (ABF) {
#pragma unroll
            for (int j = 0; j < 4; ++j) *(i32x4*)&a_b[j * 8] = *(const i32x4*)(Ab + base + j * 8);
        } else {
#pragma unroll
            for (int j = 0; j < 8; ++j) *(f32x4*)&a_f[j * 4] = *(const f32x4*)(Af + base + j * 4);
        }
    };
    auto loadB = [&](int kt) {
        size_t base = (size_t)(n0 + srow) * K + (size_t)kt * 64 + shalf;
        if (BBF) {
#pragma unroll
            for (int j = 0; j < 4; ++j) *(i32x4*)&b_b[j * 8] = *(const i32x4*)(Bb + base + j * 8);
        } else {
#pragma unroll
            for (int j = 0; j < 8; ++j) *(f32x4*)&b_f[j * 4] = *(const f32x4*)(Bf + base + j * 4);
        }
    };
    auto storeA = [&](int buf) {
        unsigned short tA[32];
        if (ABF) {
#pragma unroll
            for (int j = 0; j < 32; ++j) tA[j] = a_b[j];
        } else {
#pragma unroll
            for (int j = 0; j < 32; ++j) tA[j] = f2bf(a_f[j]);
        }
#pragma unroll
        for (int j = 0; j < 4; ++j) *(i32x4*)&As[buf][srow][shalf + j * 8] = *(i32x4*)&tA[j * 8];
    };
    auto storeB = [&](int buf) {
        unsigned short tB[32];
        if (BBF) {
#pragma unroll
            for (int j = 0; j < 32; ++j) tB[j] = b_b[j];
        } else {
#pragma unroll
            for (int j = 0; j < 32; ++j) tB[j] = f2bf(b_f[j]);
        }
#pragma unroll
        for (int j = 0; j < 4; ++j) *(i32x4*)&Bs[buf][srow][shalf + j * 8] = *(i32x4*)&tB[j * 8];
    };

    const int nkt = K >> 6;

    loadA(0); loadB(0);
    storeA(0); storeB(0);
    __syncthreads();

    for (int kt = 0; kt < nkt; ++kt) {
        const int cur = kt & 1;
        if (kt + 1 < nkt) { loadA(kt + 1); loadB(kt + 1); }
#pragma unroll
        for (int ks = 0; ks < 2; ++ks) {
            bf16x8 av[2], bv[8];
#pragma unroll
            for (int mi = 0; mi < 2; ++mi)
                av[mi] = *(const bf16x8*)&As[cur][wid * 32 + mi * 16 + fr][ks * 32 + fg * 8];
#pragma unroll
            for (int ni = 0; ni < 8; ++ni)
                bv[ni] = *(const bf16x8*)&Bs[cur][ni * 16 + fr][ks * 32 + fg * 8];
#pragma unroll
            for (int mi = 0; mi < 2; ++mi)
#pragma unroll
                for (int ni = 0; ni < 8; ++ni)
                    acc[mi][ni] = __builtin_amdgcn_mfma_f32_16x16x32_bf16(av[mi], bv[ni], acc[mi][ni], 0, 0, 0);
        }
        if (kt + 1 < nkt) { storeA(cur ^ 1); storeB(cur ^ 1); }
        __syncthreads();
    }

    if (EPI == 0) {
#pragma unroll
        for (int mi = 0; mi < 2; ++mi)
#pragma unroll
            for (int r = 0; r < 4; ++r) {
                const int m = m0 + wid * 32 + mi * 16 + fg * 4 + r;
#pragma unroll
                for (int ni = 0; ni < 8; ++ni) {
                    const int col = n0 + ni * 16 + fr;
                    Cout[(size_t)m * N + col] = acc[mi][ni][r] + bias[col];
                }
            }
    } else if (EPI == 1) {
        float wsv[8];
#pragma unroll
        for (int ni = 0; ni < 8; ++ni) wsv[ni] = wscore[n0 + ni * 16 + fr];
#pragma unroll
        for (int mi = 0; mi < 2; ++mi)
#pragma unroll
            for (int r = 0; r < 4; ++r) {
                const int m = m0 + wid * 32 + mi * 16 + fg * 4 + r;
                const int bb = m & 255, tt = m >> 8;
                const float* hp = hproj + (size_t)bb * 1024 + n0 + fr;
                float s = 0.f;
#pragma unroll
                for (int ni = 0; ni < 8; ++ni)
                    s += fast_tanh(acc[mi][ni][r] + hp[ni * 16]) * wsv[ni];
                s += __shfl_xor(s, 1); s += __shfl_xor(s, 2);
                s += __shfl_xor(s, 4); s += __shfl_xor(s, 8);
                if (fr == 0) epart[((size_t)bb * 256 + tt) * 8 + nb] = s;
            }
    } else {
#pragma unroll
        for (int mi = 0; mi < 2; ++mi)
#pragma unroll
            for (int r = 0; r < 4; ++r) {
                const int m = m0 + wid * 32 + mi * 16 + fg * 4 + r;
                float vv[8];
                float mx = -3.4e38f;
#pragma unroll
                for (int ni = 0; ni < 8; ++ni) {
                    const int col = n0 + ni * 16 + fr;
                    vv[ni] = acc[mi][ni][r] + bias[col];
                    Cout[(size_t)m * N + col] = vv[ni];
                    mx = fmaxf(mx, vv[ni]);
                }
                mx = fmaxf(mx, __shfl_xor(mx, 1));
                mx = fmaxf(mx, __shfl_xor(mx, 2));
                mx = fmaxf(mx, __shfl_xor(mx, 4));
                mx = fmaxf(mx, __shfl_xor(mx, 8));
                float se = 0.f;
#pragma unroll
                for (int ni = 0; ni < 8; ++ni) se += __expf(vv[ni] - mx);
                se += __shfl_xor(se, 1); se += __shfl_xor(se, 2);
                se += __shfl_xor(se, 4); se += __shfl_xor(se, 8);
                if (fr == 0) {
                    lsepart[((size_t)m * nbn + nb) * 2]     = mx;
                    lsepart[((size_t)m * nbn + nb) * 2 + 1] = se;
                }
            }
    }
}

// ---------------------------------------------------------------------------
// enc f32 -> bf16, branch-free stream (16.78M float4s)
// ---------------------------------------------------------------------------
__global__ void enc_conv(const float* __restrict__ enc, unsigned short* __restrict__ encB)
{
    for (int i = blockIdx.x * 256 + threadIdx.x; i < 16777216; i += gridDim.x * 256) {
        f32x4 v = *(const f32x4*)(enc + (size_t)i * 4);
        u16x4 o;
#pragma unroll
        for (int j = 0; j < 4; ++j) o[j] = f2bf(v[j]);
        *(u16x4*)(encB + (size_t)i * 4) = o;
    }
}

// W_i2h conv + emb gather
__global__ void prep_kernel(const float* __restrict__ Wi2h, unsigned short* __restrict__ WiB,
                            const float* __restrict__ emb, const int* __restrict__ tokens,
                            unsigned short* __restrict__ xB)
{
    int i = blockIdx.x * 256 + threadIdx.x;
    if (i < 262144) {
        f32x4 v = *(const f32x4*)(Wi2h + (size_t)i * 4);
        u16x4 o;
#pragma unroll
        for (int j = 0; j < 4; ++j) o[j] = f2bf(v[j]);
        *(u16x4*)(WiB + (size_t)i * 4) = o;
    } else {
        int j = i - 262144;
        int b = j >> 8, h4 = j & 255;
        int tok = tokens[b];
        f32x4 v = *(const f32x4*)(emb + (size_t)tok * 1024 + h4 * 4);
        u16x4 o;
#pragma unroll
        for (int jj = 0; jj < 4; ++jj) o[jj] = f2bf(v[jj]);
        *(u16x4*)(xB + (size_t)b * 2048 + 1024 + h4 * 4) = o;
    }
}

// softmax over t per batch b; epart is [b][t][8] partials
__global__ __launch_bounds__(256) void softmax_alpha(const float* __restrict__ epart,
                                                     float* __restrict__ alpha)
{
    const int b = blockIdx.x, t = threadIdx.x;
    const int lane = t & 63, w = t >> 6;
    const float* ep = epart + ((size_t)b * 256 + t) * 8;
    float s = 0.f;
#pragma unroll
    for (int j = 0; j < 8; ++j) s += ep[j];
    __shared__ float rmax[4], rsum[4];
    float mx = s;
#pragma unroll
    for (int d = 1; d < 64; d <<= 1) mx = fmaxf(mx, __shfl_xor(mx, d));
    if (lane == 0) rmax[w] = mx;
    __syncthreads();
    mx = fmaxf(fmaxf(rmax[0], rmax[1]), fmaxf(rmax[2], rmax[3]));
    float p = __expf(s - mx);
    float sm = p;
#pragma unroll
    for (int d = 1; d < 64; d <<= 1) sm += __shfl_xor(sm, d);
    if (lane == 0) rsum[w] = sm;
    __syncthreads();
    sm = rsum[0] + rsum[1] + rsum[2] + rsum[3];
    alpha[(size_t)b * 256 + t] = p / sm;
}

// context partials from bf16 enc
__global__ __launch_bounds__(128) void ctx_part_bf(const float* __restrict__ alpha,
                                                   const unsigned short* __restrict__ encB,
                                                   float* __restrict__ pc)
{
    const int b = blockIdx.x, tc = blockIdx.y;
    const int h8 = threadIdx.x;
    const float* al = alpha + (size_t)b * 256 + tc * 64;
    float acc[8];
#pragma unroll
    for (int j = 0; j < 8; ++j) acc[j] = 0.f;
#pragma unroll 4
    for (int i = 0; i < 64; ++i) {
        float a = al[i];
        u16x8 e = *(const u16x8*)(encB + ((size_t)(tc * 64 + i) * 256 + b) * 1024 + h8 * 8);
#pragma unroll
        for (int j = 0; j < 8; ++j) acc[j] += bf2f(e[j]) * a;
    }
    float* d = pc + ((size_t)tc * 256 + b) * 1024 + h8 * 8;
    *(f32x4*)d = *(f32x4*)&acc[0];
    *(f32x4*)(d + 4) = *(f32x4*)&acc[4];
}

// fallback f32 ctx_part
__global__ __launch_bounds__(256) void ctx_part(const float* __restrict__ alpha,
                                                const float* __restrict__ enc,
                                                float* __restrict__ pc)
{
    const int b = blockIdx.x, tc = blockIdx.y;
    const int h4 = threadIdx.x;
    const float* al = alpha + (size_t)b * 256 + tc * 64;
    f32x4 acc = {0.f, 0.f, 0.f, 0.f};
#pragma unroll 4
    for (int i = 0; i < 64; ++i) {
        float a = al[i];
        f32x4 e = *(const f32x4*)(enc + ((size_t)(tc * 64 + i) * 256 + b) * 1024 + h4 * 4);
        acc += e * a;
    }
    *(f32x4*)(pc + ((size_t)tc * 256 + b) * 1024 + h4 * 4) = acc;
}

// reduce context partials -> x_bf16[:,0:1024]
__global__ void ctx_fin(const float* __restrict__ pc, unsigned short* __restrict__ xB)
{
    const int b = blockIdx.x, h4 = threadIdx.x;
    f32x4 c = {0.f, 0.f, 0.f, 0.f};
#pragma unroll
    for (int tc = 0; tc < 4; ++tc)
        c += *(const f32x4*)(pc + ((size_t)tc * 256 + b) * 1024 + h4 * 4);
    u16x4 o;
#pragma unroll
    for (int j = 0; j < 4; ++j) o[j] = f2bf(c[j]);
    *(u16x4*)(xB + (size_t)b * 2048 + h4 * 4) = o;
}

// GRU elementwise (PyTorch gate order r,z,n)
__global__ void gru_kernel(const float* __restrict__ gi, const float* __restrict__ gh,
                           const float* __restrict__ h0, float* __restrict__ hnew,
                           unsigned short* __restrict__ hnB)
{
    int idx = blockIdx.x * 256 + threadIdx.x;
    int b = idx >> 10, h = idx & 1023;
    size_t gb = (size_t)b * 3072;
    float r = fast_sigmoid(gi[gb + h]        + gh[gb + h]);
    float z = fast_sigmoid(gi[gb + 1024 + h] + gh[gb + 1024 + h]);
    float n = fast_tanh   (gi[gb + 2048 + h] + r * gh[gb + 2048 + h]);
    float hp = h0[idx];
    float hn = (1.f - z) * n + z * hp;
    hnew[idx] = hn;
    hnB[idx] = f2bf(hn);
}

// merge per-row (max,sumexp) partials -> lse[m]
__global__ void lse_reduce(const float* __restrict__ lsepart, float* __restrict__ lse, int nbn)
{
    const int m = blockIdx.x, l = threadIdx.x;
    float mx = -3.4e38f, s = 0.f;
    for (int p = l; p < nbn; p += 64) {
        float pm = lsepart[((size_t)m * nbn + p) * 2];
        float ps = lsepart[((size_t)m * nbn + p) * 2 + 1];
        float nm = fmaxf(mx, pm);
        s = s * __expf(mx - nm) + ps * __expf(pm - nm);
        mx = nm;
    }
#pragma unroll
    for (int d = 1; d < 64; d <<= 1) {
        float om = __shfl_xor(mx, d), os = __shfl_xor(s, d);
        float nm = fmaxf(mx, om);
        s = s * __expf(mx - nm) + os * __expf(om - nm);
        mx = nm;
    }
    if (l == 0) lse[m] = mx + __logf(s);
}

// out[m,v] = logits[m,v] - lse[m]
__global__ void lsub_kernel(float* __restrict__ out, const float* __restrict__ lse)
{
    int f = blockIdx.x * 256 + threadIdx.x;
    float l = lse[f / 8000];
    f32x4 v = *(const f32x4*)(out + (size_t)f * 4);
    v -= l;
    *(f32x4*)(out + (size_t)f * 4) = v;
}

// ---------------------------------------------------------------------------
extern "C" void kernel_launch(void* const* d_in, const int* in_sizes, int n_in,
                              void* d_out, int out_size, void* d_ws, size_t ws_size,
                              hipStream_t stream)
{
    const int*   tokens  = (const int*)  d_in[0];
    const float* h0      = (const float*)d_in[1];
    const float* enc     = (const float*)d_in[2];
    const float* emb     = (const float*)d_in[3];
    const float* W_i2h   = (const float*)d_in[4];
    const float* W_h2h   = (const float*)d_in[5];
    const float* b_h2h   = (const float*)d_in[6];
    const float* w_score = (const float*)d_in[7];
    const float* W_ih    = (const float*)d_in[8];
    const float* b_ih    = (const float*)d_in[9];
    const float* W_hh    = (const float*)d_in[10];
    const float* b_hh    = (const float*)d_in[11];
    const float* W_out   = (const float*)d_in[12];
    const float* b_out   = (const float*)d_in[13];

    float* out   = (float*)d_out;
    float* hnew  = out + (size_t)256 * 32000;
    float* alpha = hnew + 256 * 1024;

    const size_t RS_LDS = 2u * 2u * 128u * LDS_STRIDE * 2u;  // 73728 B

    char* w = (char*)d_ws;
    const size_t NEED = (size_t)153 * (1 << 20);

    if (ws_size >= NEED) {
        unsigned short* encB  = (unsigned short*)(w);                           // 128 MB
        unsigned short* WiB   = (unsigned short*)(w + (size_t)128 * (1 << 20)); // 2 MB
        float* hproj          = (float*)(w + (size_t)130 * (1 << 20));          // 1 MB
        float* gh             = (float*)(w + (size_t)131 * (1 << 20));          // 3 MB
        float* epart          = (float*)(w + (size_t)134 * (1 << 20));          // 2 MB
        float* pc             = (float*)(w + (size_t)136 * (1 << 20));          // 4 MB
        unsigned short* xB    = (unsigned short*)(w + (size_t)140 * (1 << 20)); // 1 MB
        float* gi             = (float*)(w + (size_t)141 * (1 << 20));          // 3 MB
        unsigned short* hnB   = (unsigned short*)(w + (size_t)144 * (1 << 20)); // 0.5 MB
        float* lsepart        = (float*)(w + (size_t)145 * (1 << 20));          // 0.5 MB
        float* lse            = (float*)(w + (size_t)146 * (1 << 20));          // 1 KB

        enc_conv<<<2048, 256, 0, stream>>>(enc, encB);
        prep_kernel<<<1280, 256, 0, stream>>>(W_i2h, WiB, emb, tokens, xB);
        gemm_rs<0, false, false><<<16, 256, RS_LDS, stream>>>(h0, W_h2h, b_h2h, hproj,
            nullptr, nullptr, nullptr, nullptr, 256, 1024, 1024);
        gemm_rs<0, false, false><<<48, 256, RS_LDS, stream>>>(h0, W_hh, b_hh, gh,
            nullptr, nullptr, nullptr, nullptr, 256, 3072, 1024);
        gemm_lds<1><<<4096, 256, 0, stream>>>(encB, WiB, nullptr, nullptr,
            hproj, w_score, epart, nullptr, 65536, 1024, 1024);
        softmax_alpha<<<256, 256, 0, stream>>>(epart, alpha);
        ctx_part_bf<<<dim3(256, 4), 128, 0, stream>>>(alpha, encB, pc);
        ctx_fin<<<256, 256, 0, stream>>>(pc, xB);
        gemm_rs<0, true, false><<<48, 256, RS_LDS, stream>>>(xB, W_ih, b_ih, gi,
            nullptr, nullptr, nullptr, nullptr, 256, 3072, 2048);
        gru_kernel<<<1024, 256, 0, stream>>>(gi, gh, h0, hnew, hnB);
        gemm_rs<2, true, false><<<500, 256, RS_LDS, stream>>>(hnB, W_out, b_out, out,
            nullptr, nullptr, nullptr, lsepart, 256, 32000, 1024);
        lse_reduce<<<256, 64, 0, stream>>>(lsepart, lse, 250);
        lsub_kernel<<<8000, 256, 0, stream>>>(out, lse);
    } else {
        // fallback: round-1 path (18 MB workspace)
        unsigned short* WiB   = (unsigned short*)(w);
        float* hproj          = (float*)(w + (size_t)2  * (1 << 20));
        float* gh             = (float*)(w + (size_t)3  * (1 << 20));
        float* epart          = (float*)(w + (size_t)6  * (1 << 20));
        float* pc             = (float*)(w + (size_t)8  * (1 << 20));
        unsigned short* xB    = (unsigned short*)(w + (size_t)12 * (1 << 20));
        float* gi             = (float*)(w + (size_t)13 * (1 << 20));
        unsigned short* hnB   = (unsigned short*)(w + (size_t)16 * (1 << 20));
        float* lsepart        = (float*)(w + (size_t)17 * (1 << 20));
        float* lse            = (float*)(w + (size_t)18 * (1 << 20));

        prep_kernel<<<1280, 256, 0, stream>>>(W_i2h, WiB, emb, tokens, xB);
        gemm_rs<0, false, false><<<16, 256, RS_LDS, stream>>>(h0, W_h2h, b_h2h, hproj,
            nullptr, nullptr, nullptr, nullptr, 256, 1024, 1024);
        gemm_rs<0, false, false><<<48, 256, RS_LDS, stream>>>(h0, W_hh, b_hh, gh,
            nullptr, nullptr, nullptr, nullptr, 256, 3072, 1024);
        gemm_rs<1, false, true><<<4096, 256, RS_LDS, stream>>>(enc, WiB, nullptr, nullptr,
            hproj, w_score, epart, nullptr, 65536, 1024, 1024);
        softmax_alpha<<<256, 256, 0, stream>>>(epart, alpha);
        ctx_part<<<dim3(256, 4), 256, 0, stream>>>(alpha, enc, pc);
        ctx_fin<<<256, 256, 0, stream>>>(pc, xB);
        gemm_rs<0, true, false><<<48, 256, RS_LDS, stream>>>(xB, W_ih, b_ih, gi,
            nullptr, nullptr, nullptr, nullptr, 256, 3072, 2048);
        gru_kernel<<<1024, 256, 0, stream>>>(gi, gh, h0, hnew, hnB);
        gemm_rs<2, true, false><<<500, 256, RS_LDS, stream>>>(hnB, W_out, b_out, out,
            nullptr, nullptr, nullptr, lsepart, 256, 32000, 1024);
        lse_reduce<<<256, 64, 0, stream>>>(lsepart, lse, 250);
        lsub_kernel<<<8000, 256, 0, stream>>>(out, lse);
    }
}